// Round 5
// baseline (339.440 us; speedup 1.0000x reference)
//
#include <hip/hip_runtime.h>
#include <hip/hip_fp16.h>

#define N_NODES   65536
#define N_EDGES   524288
#define IN_DIM    64
#define HID       128
#define NPG       1024
#define NGRAPH    64
#define EPS       1e-5f
#define CAP       64   // bucket capacity per node (Poisson(8) tail << 64)

typedef __attribute__((ext_vector_type(8))) _Float16 f16x8;
typedef __attribute__((ext_vector_type(4))) float f32x4;

// packed fp16 pair <-> float2
static __device__ __forceinline__ float2 h2f2(unsigned int u) {
    union { unsigned int u; __half2 h; } cv;
    cv.u = u;
    return __half22float2(cv.h);
}
static __device__ __forceinline__ unsigned int f2h2(float a, float b) {
    union { __half2 h; unsigned int u; } cv;
    cv.h = __floats2half2_rn(a, b);
    return cv.u;
}

// ---------------- bucket-CSR build (ushort payload); also zeroes both ui dummy rows ----------------
__global__ __launch_bounds__(256) void fillcsr_kernel(const int* __restrict__ src, const int* __restrict__ dst,
                                                      int* __restrict__ cnt, unsigned short* __restrict__ csr,
                                                      unsigned int* __restrict__ dummyA,
                                                      unsigned int* __restrict__ dummyB) {
    if (blockIdx.x == 0) {
        if (threadIdx.x < 64) dummyA[threadIdx.x] = 0u;
        else if (threadIdx.x < 128) dummyB[threadIdx.x - 64] = 0u;
    }
    int e = blockIdx.x * 256 + threadIdx.x;
    if (e < N_EDGES) {
        int d = dst[e];
        int slot = atomicAdd(&cnt[d], 1);
        if (slot < CAP) csr[(size_t)d * CAP + slot] = (unsigned short)src[e];
    }
}

// ---------------- sort each bucket ascending by src (banded gather locality) ----------------
// Mechanism: all waves sweep e=0..len in lockstep; sorted buckets make round-e gathers the
// e-th order statistics -> concurrent address window ~6MB instead of uniform 16MB -> L2 hits.
__global__ __launch_bounds__(256) void sortcsr_kernel(const int* __restrict__ cnt,
                                                      unsigned short* __restrict__ csr) {
    __shared__ unsigned short buf[256][66];   // +2 pad: conflict-free per-thread rows
    int t = threadIdx.x;
    int n = blockIdx.x * 256 + t;
    int len = min(cnt[n], CAP);
    size_t base = (size_t)n * CAP;
    for (int i = 0; i < len; ++i) buf[t][i] = csr[base + i];
    for (int i = 1; i < len; ++i) {
        unsigned short key = buf[t][i];
        int j = i - 1;
        while (j >= 0 && buf[t][j] > key) { buf[t][j + 1] = buf[t][j]; --j; }
        buf[t][j + 1] = key;
    }
    for (int i = 0; i < len; ++i) csr[base + i] = buf[t][i];
}

// ---------------- weight prepack: split fp16 (hi+lo) in MFMA B-fragment order ----------------
__global__ __launch_bounds__(256) void pack_kernel(const float* __restrict__ Wl, const float* __restrict__ Wa,
                                                   const float* __restrict__ Wp,
                                                   _Float16* __restrict__ BhL, _Float16* __restrict__ BlL,
                                                   _Float16* __restrict__ BhP, _Float16* __restrict__ BlP) {
    int id = blockIdx.x * 256 + threadIdx.x;
    if (id < 12288) {
        int L = id & 63, c = (id >> 6) & 3, t = (id >> 8) & 15, i = id >> 12;
        int n = t * 16 + (L & 15);
        int k0 = c * 32 + ((L >> 4) * 8);
        const float* W = (n < HID) ? (Wl + (size_t)i * HID * HID + n)
                                   : (Wa + (size_t)i * HID * HID + (n - HID));
        f16x8 vh, vl;
#pragma unroll
        for (int j = 0; j < 8; ++j) {
            float w = W[(size_t)(k0 + j) * HID];
            _Float16 h = (_Float16)w;
            vh[j] = h;
            vl[j] = (_Float16)(w - (float)h);
        }
        *(f16x8*)&BhL[(size_t)id * 8] = vh;
        *(f16x8*)&BlL[(size_t)id * 8] = vl;
    } else if (id < 12288 + 1024) {
        int p = id - 12288;
        int L = p & 63, c = (p >> 6) & 1, t = (p >> 7) & 7;
        int n = t * 16 + (L & 15);
        int k0 = c * 32 + ((L >> 4) * 8);
        f16x8 vh, vl;
#pragma unroll
        for (int j = 0; j < 8; ++j) {
            float w = Wp[(size_t)(k0 + j) * HID + n];
            _Float16 h = (_Float16)w;
            vh[j] = h;
            vl[j] = (_Float16)(w - (float)h);
        }
        *(f16x8*)&BhP[(size_t)p * 8] = vh;
        *(f16x8*)&BlP[(size_t)p * 8] = vl;
    }
}

// ---------------- shared: aggregate 4 nodes (one wave-lane slice, 2 cols/lane) ----------------
// csr/xi loads are NONTEMPORAL (streamed once) so L2 stays dedicated to the ui gather band.
static __device__ __forceinline__ void agg_block4(
        int nbase, int lane,
        const int* __restrict__ cnt, const unsigned short* __restrict__ csr,
        const unsigned int* __restrict__ xi32, const unsigned int* __restrict__ ui32,
        float2* __restrict__ usum, float2* __restrict__ xv) {
    int4 c4 = *(const int4*)&cnt[nbase];
    int len0 = min(c4.x, CAP), len1 = min(c4.y, CAP),
        len2 = min(c4.z, CAP), len3 = min(c4.w, CAP);
    int maxlen = max(max(len0, len1), max(len2, len3));
    unsigned int xu[4];
#pragma unroll
    for (int p = 0; p < 4; ++p)
        xu[p] = __builtin_nontemporal_load(&xi32[(size_t)(nbase + p) * 64 + lane]);
    float ax[4] = {0.f, 0.f, 0.f, 0.f}, ay[4] = {0.f, 0.f, 0.f, 0.f};
    size_t eb = (size_t)nbase * CAP;
    for (int e = 0; e < maxlen; e += 4) {
        unsigned long long cc0 = __builtin_nontemporal_load((const unsigned long long*)&csr[eb + 0 * CAP + e]);
        unsigned long long cc1 = __builtin_nontemporal_load((const unsigned long long*)&csr[eb + 1 * CAP + e]);
        unsigned long long cc2 = __builtin_nontemporal_load((const unsigned long long*)&csr[eb + 2 * CAP + e]);
        unsigned long long cc3 = __builtin_nontemporal_load((const unsigned long long*)&csr[eb + 3 * CAP + e]);
        int idx[4][4];
        idx[0][0] = (e + 0 < len0) ? (int)(cc0 & 0xFFFFu)         : N_NODES;
        idx[0][1] = (e + 1 < len0) ? (int)((cc0 >> 16) & 0xFFFFu) : N_NODES;
        idx[0][2] = (e + 2 < len0) ? (int)((cc0 >> 32) & 0xFFFFu) : N_NODES;
        idx[0][3] = (e + 3 < len0) ? (int)((cc0 >> 48) & 0xFFFFu) : N_NODES;
        idx[1][0] = (e + 0 < len1) ? (int)(cc1 & 0xFFFFu)         : N_NODES;
        idx[1][1] = (e + 1 < len1) ? (int)((cc1 >> 16) & 0xFFFFu) : N_NODES;
        idx[1][2] = (e + 2 < len1) ? (int)((cc1 >> 32) & 0xFFFFu) : N_NODES;
        idx[1][3] = (e + 3 < len1) ? (int)((cc1 >> 48) & 0xFFFFu) : N_NODES;
        idx[2][0] = (e + 0 < len2) ? (int)(cc2 & 0xFFFFu)         : N_NODES;
        idx[2][1] = (e + 1 < len2) ? (int)((cc2 >> 16) & 0xFFFFu) : N_NODES;
        idx[2][2] = (e + 2 < len2) ? (int)((cc2 >> 32) & 0xFFFFu) : N_NODES;
        idx[2][3] = (e + 3 < len2) ? (int)((cc2 >> 48) & 0xFFFFu) : N_NODES;
        idx[3][0] = (e + 0 < len3) ? (int)(cc3 & 0xFFFFu)         : N_NODES;
        idx[3][1] = (e + 1 < len3) ? (int)((cc3 >> 16) & 0xFFFFu) : N_NODES;
        idx[3][2] = (e + 2 < len3) ? (int)((cc3 >> 32) & 0xFFFFu) : N_NODES;
        idx[3][3] = (e + 3 < len3) ? (int)((cc3 >> 48) & 0xFFFFu) : N_NODES;
        unsigned int uu[4][4];
#pragma unroll
        for (int p = 0; p < 4; ++p)
#pragma unroll
            for (int j = 0; j < 4; ++j)
                uu[p][j] = ui32[(size_t)idx[p][j] * 64 + lane];
#pragma unroll
        for (int p = 0; p < 4; ++p) {
            float2 v0 = h2f2(uu[p][0]), v1 = h2f2(uu[p][1]),
                   v2 = h2f2(uu[p][2]), v3 = h2f2(uu[p][3]);
            ax[p] += (v0.x + v1.x) + (v2.x + v3.x);
            ay[p] += (v0.y + v1.y) + (v2.y + v3.y);
        }
    }
#pragma unroll
    for (int p = 0; p < 4; ++p) {
        float2 xf = h2f2(xu[p]);
        usum[p] = make_float2(ax[p], ay[p]);
        xv[p] = make_float2(fmaxf(xf.x + ax[p], 0.f), fmaxf(xf.y + ay[p], 0.f));
    }
}

// ---------------- shared: half-GEMM (8 t-tiles) for one 32-row band, A in LDS ----------------
// xi stores nontemporal (sequentially consumed next kernel); ui stores cached (gather target).
static __device__ __forceinline__ void gemm_from_lds_half(
        const _Float16 (*x_sm)[136], int band, int tbase, int L,
        const _Float16* __restrict__ Bh, const _Float16* __restrict__ Bl,
        const float* __restrict__ bl_, const float* __restrict__ ba_,
        int R0, _Float16* __restrict__ xi16, _Float16* __restrict__ ui16) {
    int m = L & 15, q = L >> 4;
    int Rw = R0 + band * 32;
    f16x8 a[2][4];
#pragma unroll
    for (int rt = 0; rt < 2; ++rt)
#pragma unroll
        for (int c = 0; c < 4; ++c)
            a[rt][c] = *(const f16x8*)&x_sm[band * 32 + rt * 16 + m][c * 32 + q * 8];
    // tbase==0 -> xi half; tbase==8 -> ui half (wave-uniform)
    _Float16* dstp = tbase ? ui16 : xi16;
    const float* bb = tbase ? ba_ : bl_;
    bool is_xi = (tbase == 0);
#pragma unroll
    for (int t = 0; t < 8; ++t) {
        int tg = tbase + t;
        f32x4 a0 = (f32x4)(0.f), a1 = (f32x4)(0.f);
#pragma unroll
        for (int c = 0; c < 4; ++c) {
            f16x8 bh = *(const f16x8*)&Bh[(size_t)((tg * 4 + c) * 64 + L) * 8];
            f16x8 bl = *(const f16x8*)&Bl[(size_t)((tg * 4 + c) * 64 + L) * 8];
            a0 = __builtin_amdgcn_mfma_f32_16x16x32_f16(a[0][c], bh, a0, 0, 0, 0);
            a1 = __builtin_amdgcn_mfma_f32_16x16x32_f16(a[1][c], bh, a1, 0, 0, 0);
            a0 = __builtin_amdgcn_mfma_f32_16x16x32_f16(a[0][c], bl, a0, 0, 0, 0);
            a1 = __builtin_amdgcn_mfma_f32_16x16x32_f16(a[1][c], bl, a1, 0, 0, 0);
        }
        int dc = t * 16 + m;
        float bias = bb[dc];
#pragma unroll
        for (int r = 0; r < 4; ++r) {
            _Float16 v0 = (_Float16)(a0[r] + bias);
            _Float16 v1 = (_Float16)(a1[r] + bias);
            _Float16* p0 = &dstp[(size_t)(Rw + q * 4 + r) * HID + dc];
            _Float16* p1 = &dstp[(size_t)(Rw + 16 + q * 4 + r) * HID + dc];
            if (is_xi) {
                __builtin_nontemporal_store(v0, p0);
                __builtin_nontemporal_store(v1, p1);
            } else {
                *p0 = v0;
                *p1 = v1;
            }
        }
    }
}

// ---------------- full-GEMM helper (proj path, 256 threads) ----------------
static __device__ __forceinline__ void gemm_from_lds(
        const _Float16 (*x_sm)[136], int wv, int L,
        const _Float16* __restrict__ Bh, const _Float16* __restrict__ Bl,
        const float* __restrict__ bl_, const float* __restrict__ ba_,
        int R0, _Float16* __restrict__ xi16, _Float16* __restrict__ ui16) {
    int m = L & 15, q = L >> 4;
    int Rw = R0 + wv * 32;
    f16x8 a[2][4];
#pragma unroll
    for (int rt = 0; rt < 2; ++rt)
#pragma unroll
        for (int c = 0; c < 4; ++c)
            a[rt][c] = *(const f16x8*)&x_sm[wv * 32 + rt * 16 + m][c * 32 + q * 8];
#pragma unroll
    for (int t = 0; t < 16; ++t) {
        f32x4 a0 = (f32x4)(0.f), a1 = (f32x4)(0.f);
#pragma unroll
        for (int c = 0; c < 4; ++c) {
            f16x8 bh = *(const f16x8*)&Bh[(size_t)((t * 4 + c) * 64 + L) * 8];
            f16x8 bl = *(const f16x8*)&Bl[(size_t)((t * 4 + c) * 64 + L) * 8];
            a0 = __builtin_amdgcn_mfma_f32_16x16x32_f16(a[0][c], bh, a0, 0, 0, 0);
            a1 = __builtin_amdgcn_mfma_f32_16x16x32_f16(a[1][c], bh, a1, 0, 0, 0);
            a0 = __builtin_amdgcn_mfma_f32_16x16x32_f16(a[0][c], bl, a0, 0, 0, 0);
            a1 = __builtin_amdgcn_mfma_f32_16x16x32_f16(a[1][c], bl, a1, 0, 0, 0);
        }
        int col = t * 16 + m;
        float bias = (t < 8) ? bl_[col] : ba_[col - HID];
        _Float16* dstp = (t < 8) ? xi16 : ui16;
        int dc = (t < 8) ? col : col - HID;
#pragma unroll
        for (int r = 0; r < 4; ++r) {
            _Float16 v0 = (_Float16)(a0[r] + bias);
            _Float16 v1 = (_Float16)(a1[r] + bias);
            _Float16* p0 = &dstp[(size_t)(Rw + q * 4 + r) * HID + dc];
            _Float16* p1 = &dstp[(size_t)(Rw + 16 + q * 4 + r) * HID + dc];
            if (t < 8) {
                __builtin_nontemporal_store(v0, p0);
                __builtin_nontemporal_store(v1, p1);
            } else {
                *p0 = v0;
                *p1 = v1;
            }
        }
    }
}

__global__ __launch_bounds__(256, 2) void proj_gemm_kernel(const float* __restrict__ xin,
                                                           const _Float16* __restrict__ BhP, const _Float16* __restrict__ BlP,
                                                           const float* __restrict__ bp,
                                                           const _Float16* __restrict__ Bh1, const _Float16* __restrict__ Bl1,
                                                           const float* __restrict__ bl_, const float* __restrict__ ba_,
                                                           _Float16* __restrict__ xi16, _Float16* __restrict__ ui16) {
    __shared__ __align__(16) _Float16 x_sm[128][136];
    int tid = threadIdx.x;
    int wv = tid >> 6, L = tid & 63;
    int m = L & 15, q = L >> 4;
    int R0 = blockIdx.x * 128;
    int Rw = R0 + wv * 32;
    f16x8 ah[2][2], al[2][2];
#pragma unroll
    for (int rt = 0; rt < 2; ++rt)
#pragma unroll
        for (int c = 0; c < 2; ++c) {
            const float* p = &xin[(size_t)(Rw + rt * 16 + m) * IN_DIM + c * 32 + q * 8];
            float4 f0 = *(const float4*)p;
            float4 f1 = *(const float4*)(p + 4);
            float fv[8] = {f0.x, f0.y, f0.z, f0.w, f1.x, f1.y, f1.z, f1.w};
            f16x8 vh, vl;
#pragma unroll
            for (int j = 0; j < 8; ++j) {
                _Float16 h = (_Float16)fv[j];
                vh[j] = h;
                vl[j] = (_Float16)(fv[j] - (float)h);
            }
            ah[rt][c] = vh;
            al[rt][c] = vl;
        }
#pragma unroll
    for (int t = 0; t < 8; ++t) {
        f32x4 a0 = (f32x4)(0.f), a1 = (f32x4)(0.f);
#pragma unroll
        for (int c = 0; c < 2; ++c) {
            f16x8 bh = *(const f16x8*)&BhP[(size_t)((t * 2 + c) * 64 + L) * 8];
            f16x8 bl = *(const f16x8*)&BlP[(size_t)((t * 2 + c) * 64 + L) * 8];
            a0 = __builtin_amdgcn_mfma_f32_16x16x32_f16(ah[0][c], bh, a0, 0, 0, 0);
            a1 = __builtin_amdgcn_mfma_f32_16x16x32_f16(ah[1][c], bh, a1, 0, 0, 0);
            a0 = __builtin_amdgcn_mfma_f32_16x16x32_f16(ah[0][c], bl, a0, 0, 0, 0);
            a1 = __builtin_amdgcn_mfma_f32_16x16x32_f16(ah[1][c], bl, a1, 0, 0, 0);
            a0 = __builtin_amdgcn_mfma_f32_16x16x32_f16(al[0][c], bh, a0, 0, 0, 0);
            a1 = __builtin_amdgcn_mfma_f32_16x16x32_f16(al[1][c], bh, a1, 0, 0, 0);
        }
        int col = t * 16 + m;
        float bias = bp[col];
#pragma unroll
        for (int r = 0; r < 4; ++r) {
            x_sm[wv * 32 + q * 4 + r][col] = (_Float16)fmaxf(a0[r] + bias, 0.f);
            x_sm[wv * 32 + 16 + q * 4 + r][col] = (_Float16)fmaxf(a1[r] + bias, 0.f);
        }
    }
    __syncthreads();
    gemm_from_lds(x_sm, wv, L, Bh1, Bl1, bl_, ba_, R0, xi16, ui16);
}

// ---------------- fused aggregate + layer GEMM (128 nodes/block, 8 waves, grid 512) ----------------
__global__ __launch_bounds__(512, 4) void agg_gemm_kernel(const int* __restrict__ cnt, const unsigned short* __restrict__ csr,
                                                          const unsigned int* __restrict__ xi_prev,
                                                          const unsigned int* __restrict__ ui_prev,
                                                          const _Float16* __restrict__ Bh, const _Float16* __restrict__ Bl,
                                                          const float* __restrict__ bl_, const float* __restrict__ ba_,
                                                          _Float16* __restrict__ xi16, _Float16* __restrict__ ui16) {
    __shared__ __align__(16) _Float16 x_sm[128][136];
    int tid = threadIdx.x;
    int wv = tid >> 6, lane = tid & 63;
    int R0 = blockIdx.x * 128;
    // aggregate: wave wv owns 16 nodes
    int nb = R0 + wv * 16;
    for (int s = 0; s < 4; ++s) {
        float2 us[4], xv[4];
        agg_block4(nb + s * 4, lane, cnt, csr, xi_prev, ui_prev, us, xv);
#pragma unroll
        for (int p = 0; p < 4; ++p)
            *(unsigned int*)&x_sm[wv * 16 + s * 4 + p][lane * 2] = f2h2(xv[p].x, xv[p].y);
    }
    __syncthreads();
    // GEMM: wave-pair decomposition (band = wv>>1, t-half = wv&1)
    gemm_from_lds_half(x_sm, wv >> 1, (wv & 1) * 8, lane, Bh, Bl, bl_, ba_, R0, xi16, ui16);
}

// ---------------- final aggregate (512 threads, 128 nodes/block): x -> global, u_g, BN stats ----------------
__global__ __launch_bounds__(512, 4) void agg_final_kernel(const int* __restrict__ cnt, const unsigned short* __restrict__ csr,
                                                           const unsigned int* __restrict__ xi_prev,
                                                           const unsigned int* __restrict__ ui_prev,
                                                           unsigned int* __restrict__ x32out,
                                                           float* __restrict__ u_g,
                                                           float* __restrict__ sums, float* __restrict__ sq) {
    __shared__ float red[8][64][6];
    int tid = threadIdx.x;
    int wv = tid >> 6, lane = tid & 63;
    int nb = blockIdx.x * 128 + wv * 16;
    float gx = 0.f, gy = 0.f, s0 = 0.f, s1 = 0.f, q0 = 0.f, q1 = 0.f;
    for (int s = 0; s < 4; ++s) {
        float2 us[4], xv[4];
        agg_block4(nb + s * 4, lane, cnt, csr, xi_prev, ui_prev, us, xv);
#pragma unroll
        for (int p = 0; p < 4; ++p) {
            __builtin_nontemporal_store(f2h2(xv[p].x, xv[p].y),
                                        &x32out[(size_t)(nb + s * 4 + p) * 64 + lane]);
            gx += us[p].x; gy += us[p].y;
            s0 += xv[p].x; s1 += xv[p].y;
            q0 += xv[p].x * xv[p].x; q1 += xv[p].y * xv[p].y;
        }
    }
    red[wv][lane][0] = gx; red[wv][lane][1] = gy;
    red[wv][lane][2] = s0; red[wv][lane][3] = s1;
    red[wv][lane][4] = q0; red[wv][lane][5] = q1;
    __syncthreads();
    if (tid < 64) {
        int t = tid;
        float G0 = 0.f, G1 = 0.f, S0 = 0.f, S1 = 0.f, Q0 = 0.f, Q1 = 0.f;
#pragma unroll
        for (int w = 0; w < 8; ++w) {
            G0 += red[w][t][0]; G1 += red[w][t][1];
            S0 += red[w][t][2]; S1 += red[w][t][3];
            Q0 += red[w][t][4]; Q1 += red[w][t][5];
        }
        int g = blockIdx.x >> 3;   // 128 nodes/block, 8 blocks/graph
        atomicAdd(&u_g[g * HID + t * 2], G0);
        atomicAdd(&u_g[g * HID + t * 2 + 1], G1);
        atomicAdd(&sums[t * 2], S0);
        atomicAdd(&sums[t * 2 + 1], S1);
        atomicAdd(&sq[t * 2], Q0);
        atomicAdd(&sq[t * 2 + 1], Q1);
    }
}

// ---------------- finalize: BN coefs P, const, per-graph S ----------------
__global__ __launch_bounds__(256) void finalize_kernel(const float* __restrict__ sums, const float* __restrict__ sq,
                                                       const float* __restrict__ u_g,
                                                       const float* __restrict__ gamma, const float* __restrict__ beta,
                                                       const float* __restrict__ Wf, const float* __restrict__ bf,
                                                       float* __restrict__ P, float* __restrict__ constv,
                                                       float* __restrict__ S) {
    __shared__ float red0[256], red1[256];
    int c = threadIdx.x;
    float mean, var;
    if (c < HID) {
        mean = sums[c] * (1.f / N_NODES);
        var = sq[c] * (1.f / N_NODES) - mean * mean;
    } else {
        int d = c - HID;
        float s = 0.f, s2 = 0.f;
        for (int g = 0; g < NGRAPH; ++g) {
            float v = u_g[g * HID + d];
            s += v; s2 += v * v;
        }
        mean = s * (1.f / NGRAPH);
        var = s2 * (1.f / NGRAPH) - mean * mean;
    }
    float a = gamma[c] * rsqrtf(var + EPS);
    float bsh = beta[c] - mean * a;
    float w0 = Wf[c * 2], w1 = Wf[c * 2 + 1];
    P[c * 2] = a * w0;
    P[c * 2 + 1] = a * w1;
    red0[c] = bsh * w0;
    red1[c] = bsh * w1;
    __syncthreads();
    for (int off = 128; off > 0; off >>= 1) {
        if (c < off) { red0[c] += red0[c + off]; red1[c] += red1[c + off]; }
        __syncthreads();
    }
    if (c == 0) {
        constv[0] = bf[0] + red0[0];
        constv[1] = bf[1] + red1[0];
    }
    __syncthreads();
    if (c < NGRAPH * 2) {
        int g = c >> 1, j = c & 1;
        float s = 0.f;
        for (int d = 0; d < HID; ++d) s += u_g[g * HID + d] * P[(HID + d) * 2 + j];
        S[g * 2 + j] = s;
    }
}

// ---------------- final: out[n][j] = sum_c x[n][c]*P[c][j] + S[g][j] + const[j] ----------------
__global__ __launch_bounds__(256) void final_kernel(const unsigned int* __restrict__ x32,
                                                    const float* __restrict__ P,
                                                    const float* __restrict__ S, const float* __restrict__ constv,
                                                    float* __restrict__ out) {
    int tid = threadIdx.x;
    int row = blockIdx.x * 4 + (tid >> 6);
    int lane = tid & 63;
    float2 v = h2f2(__builtin_nontemporal_load(&x32[(size_t)row * 64 + lane]));
    float4 p = *(const float4*)&P[lane * 4];
    float a0 = v.x * p.x + v.y * p.z;
    float a1 = v.x * p.y + v.y * p.w;
#pragma unroll
    for (int off = 32; off > 0; off >>= 1) {
        a0 += __shfl_down(a0, off);
        a1 += __shfl_down(a1, off);
    }
    if (lane == 0) {
        int g = row >> 10;
        float2 o;
        o.x = a0 + S[g * 2] + constv[0];
        o.y = a1 + S[g * 2 + 1] + constv[1];
        *(float2*)&out[(size_t)row * 2] = o;
    }
}

extern "C" void kernel_launch(void* const* d_in, const int* in_sizes, int n_in,
                              void* d_out, int out_size, void* d_ws, size_t ws_size,
                              hipStream_t stream) {
    const float* x_in   = (const float*)d_in[0];
    const int*   ei     = (const int*)d_in[1];
    const float* W_proj = (const float*)d_in[3];
    const float* b_proj = (const float*)d_in[4];
    const float* W_lay  = (const float*)d_in[5];
    const float* b_lay  = (const float*)d_in[6];
    const float* W_aggr = (const float*)d_in[7];
    const float* b_aggr = (const float*)d_in[8];
    const float* gamma  = (const float*)d_in[9];
    const float* beta   = (const float*)d_in[10];
    const float* W_fin  = (const float*)d_in[11];
    const float* b_fin  = (const float*)d_in[12];
    float* out = (float*)d_out;

    const int* src = ei;
    const int* dst = ei + N_EDGES;

    const size_t NM = (size_t)N_NODES * HID;
    _Float16* xiA = (_Float16*)d_ws;           // 16MB
    _Float16* uiA = xiA + NM;                  // 16MB + dummy row
    _Float16* xiB = uiA + NM + HID;            // 16MB
    _Float16* uiB = xiB + NM;                  // 16MB + dummy row
    _Float16* xF  = uiB + NM + HID;            // 16MB (final x for BN/final)
    _Float16* BhL = xF + NM;                   // 98304
    _Float16* BlL = BhL + 98304;
    _Float16* BhP = BlL + 98304;               // 8192
    _Float16* BlP = BhP + 8192;
    int* cnt = (int*)(BlP + 8192);             // 65536 ints
    unsigned short* csr = (unsigned short*)(cnt + N_NODES);  // 65536*64 ushort (8.4MB)
    float* u_g    = (float*)(csr + (size_t)N_NODES * CAP);   // 8192
    float* sums   = u_g + NGRAPH * HID;        // 128
    float* sq     = sums + HID;                // 128
    float* P      = sq + HID;                  // 512
    float* constv = P + 512;                   // 2
    float* S      = constv + 2;                // 128

    hipMemsetAsync(cnt, 0, (size_t)N_NODES * sizeof(int), stream);
    hipMemsetAsync(u_g, 0, (size_t)(NGRAPH * HID + 2 * HID) * sizeof(float), stream);

    fillcsr_kernel<<<N_EDGES / 256, 256, 0, stream>>>(src, dst, cnt, csr,
                                                      (unsigned int*)(uiA + NM),
                                                      (unsigned int*)(uiB + NM));

    sortcsr_kernel<<<N_NODES / 256, 256, 0, stream>>>(cnt, csr);

    pack_kernel<<<52, 256, 0, stream>>>(W_lay, W_aggr, W_proj, BhL, BlL, BhP, BlP);

    // layer 1: proj (LDS) + GEMM1 -> xiA/uiA
    proj_gemm_kernel<<<N_NODES / 128, 256, 0, stream>>>(
        x_in, BhP, BlP, b_proj,
        BhL, BlL, b_lay, b_aggr, xiA, uiA);

    // layer 2: aggregate(uiA)+xiA (LDS) + GEMM2 -> xiB/uiB
    agg_gemm_kernel<<<N_NODES / 128, 512, 0, stream>>>(
        cnt, csr, (const unsigned int*)xiA, (const unsigned int*)uiA,
        BhL + (size_t)1 * 4096 * 8, BlL + (size_t)1 * 4096 * 8,
        b_lay + HID, b_aggr + HID, xiB, uiB);

    // layer 3: aggregate(uiB)+xiB (LDS) + GEMM3 -> xiA/uiA
    agg_gemm_kernel<<<N_NODES / 128, 512, 0, stream>>>(
        cnt, csr, (const unsigned int*)xiB, (const unsigned int*)uiB,
        BhL + (size_t)2 * 4096 * 8, BlL + (size_t)2 * 4096 * 8,
        b_lay + 2 * HID, b_aggr + 2 * HID, xiA, uiA);

    // final aggregate: x -> xF, u_g accum, fused BN column stats
    agg_final_kernel<<<N_NODES / 128, 512, 0, stream>>>(
        cnt, csr, (const unsigned int*)xiA, (const unsigned int*)uiA,
        (unsigned int*)xF, u_g, sums, sq);

    finalize_kernel<<<1, 256, 0, stream>>>(sums, sq, u_g, gamma, beta, W_fin, b_fin, P, constv, S);
    final_kernel<<<N_NODES / 4, 256, 0, stream>>>((const unsigned int*)xF, P, S, constv, out);
}

// Round 7
// 314.354 us; speedup vs baseline: 1.0798x; 1.0798x over previous
//
#include <hip/hip_runtime.h>
#include <hip/hip_fp16.h>

#define N_NODES   65536
#define N_EDGES   524288
#define IN_DIM    64
#define HID       128
#define NPG       1024
#define NGRAPH    64
#define EPS       1e-5f
#define CAP       64   // bucket capacity per node (Poisson(8) tail << 64)

typedef __attribute__((ext_vector_type(8))) _Float16 f16x8;
typedef __attribute__((ext_vector_type(4))) float f32x4;

// packed fp16 pair <-> float2
static __device__ __forceinline__ float2 h2f2(unsigned int u) {
    union { unsigned int u; __half2 h; } cv;
    cv.u = u;
    return __half22float2(cv.h);
}
static __device__ __forceinline__ unsigned int f2h2(float a, float b) {
    union { __half2 h; unsigned int u; } cv;
    cv.h = __floats2half2_rn(a, b);
    return cv.u;
}

// ---------------- bucket-CSR build (ushort payload); also zeroes both ui dummy rows ----------------
__global__ __launch_bounds__(256) void fillcsr_kernel(const int* __restrict__ src, const int* __restrict__ dst,
                                                      int* __restrict__ cnt, unsigned short* __restrict__ csr,
                                                      unsigned int* __restrict__ dummyA,
                                                      unsigned int* __restrict__ dummyB) {
    if (blockIdx.x == 0) {
        if (threadIdx.x < 64) dummyA[threadIdx.x] = 0u;
        else if (threadIdx.x < 128) dummyB[threadIdx.x - 64] = 0u;
    }
    int e = blockIdx.x * 256 + threadIdx.x;
    if (e < N_EDGES) {
        int d = dst[e];
        int slot = atomicAdd(&cnt[d], 1);
        if (slot < CAP) csr[(size_t)d * CAP + slot] = (unsigned short)src[e];
    }
}

// ---------------- weight prepack: split fp16 (hi+lo) in MFMA B-fragment order ----------------
__global__ __launch_bounds__(256) void pack_kernel(const float* __restrict__ Wl, const float* __restrict__ Wa,
                                                   const float* __restrict__ Wp,
                                                   _Float16* __restrict__ BhL, _Float16* __restrict__ BlL,
                                                   _Float16* __restrict__ BhP, _Float16* __restrict__ BlP) {
    int id = blockIdx.x * 256 + threadIdx.x;
    if (id < 12288) {
        int L = id & 63, c = (id >> 6) & 3, t = (id >> 8) & 15, i = id >> 12;
        int n = t * 16 + (L & 15);
        int k0 = c * 32 + ((L >> 4) * 8);
        const float* W = (n < HID) ? (Wl + (size_t)i * HID * HID + n)
                                   : (Wa + (size_t)i * HID * HID + (n - HID));
        f16x8 vh, vl;
#pragma unroll
        for (int j = 0; j < 8; ++j) {
            float w = W[(size_t)(k0 + j) * HID];
            _Float16 h = (_Float16)w;
            vh[j] = h;
            vl[j] = (_Float16)(w - (float)h);
        }
        *(f16x8*)&BhL[(size_t)id * 8] = vh;
        *(f16x8*)&BlL[(size_t)id * 8] = vl;
    } else if (id < 12288 + 1024) {
        int p = id - 12288;
        int L = p & 63, c = (p >> 6) & 1, t = (p >> 7) & 7;
        int n = t * 16 + (L & 15);
        int k0 = c * 32 + ((L >> 4) * 8);
        f16x8 vh, vl;
#pragma unroll
        for (int j = 0; j < 8; ++j) {
            float w = Wp[(size_t)(k0 + j) * HID + n];
            _Float16 h = (_Float16)w;
            vh[j] = h;
            vl[j] = (_Float16)(w - (float)h);
        }
        *(f16x8*)&BhP[(size_t)p * 8] = vh;
        *(f16x8*)&BlP[(size_t)p * 8] = vl;
    }
}

// ---------------- shared: aggregate 4 nodes (one wave-lane slice, 2 cols/lane) ----------------
static __device__ __forceinline__ void agg_block4(
        int nbase, int lane,
        const int* __restrict__ cnt, const unsigned short* __restrict__ csr,
        const unsigned int* __restrict__ xi32, const unsigned int* __restrict__ ui32,
        float2* __restrict__ usum, float2* __restrict__ xv) {
    int4 c4 = *(const int4*)&cnt[nbase];
    int len0 = min(c4.x, CAP), len1 = min(c4.y, CAP),
        len2 = min(c4.z, CAP), len3 = min(c4.w, CAP);
    int maxlen = max(max(len0, len1), max(len2, len3));
    unsigned int xu[4];
#pragma unroll
    for (int p = 0; p < 4; ++p) xu[p] = xi32[(size_t)(nbase + p) * 64 + lane];
    float ax[4] = {0.f, 0.f, 0.f, 0.f}, ay[4] = {0.f, 0.f, 0.f, 0.f};
    size_t eb = (size_t)nbase * CAP;
    for (int e = 0; e < maxlen; e += 4) {
        uint2 c0 = *(const uint2*)&csr[eb + 0 * CAP + e];
        uint2 c1 = *(const uint2*)&csr[eb + 1 * CAP + e];
        uint2 c2 = *(const uint2*)&csr[eb + 2 * CAP + e];
        uint2 c3 = *(const uint2*)&csr[eb + 3 * CAP + e];
        int idx[4][4];
        idx[0][0] = (e + 0 < len0) ? (int)(c0.x & 0xFFFFu) : N_NODES;
        idx[0][1] = (e + 1 < len0) ? (int)(c0.x >> 16)     : N_NODES;
        idx[0][2] = (e + 2 < len0) ? (int)(c0.y & 0xFFFFu) : N_NODES;
        idx[0][3] = (e + 3 < len0) ? (int)(c0.y >> 16)     : N_NODES;
        idx[1][0] = (e + 0 < len1) ? (int)(c1.x & 0xFFFFu) : N_NODES;
        idx[1][1] = (e + 1 < len1) ? (int)(c1.x >> 16)     : N_NODES;
        idx[1][2] = (e + 2 < len1) ? (int)(c1.y & 0xFFFFu) : N_NODES;
        idx[1][3] = (e + 3 < len1) ? (int)(c1.y >> 16)     : N_NODES;
        idx[2][0] = (e + 0 < len2) ? (int)(c2.x & 0xFFFFu) : N_NODES;
        idx[2][1] = (e + 1 < len2) ? (int)(c2.x >> 16)     : N_NODES;
        idx[2][2] = (e + 2 < len2) ? (int)(c2.y & 0xFFFFu) : N_NODES;
        idx[2][3] = (e + 3 < len2) ? (int)(c2.y >> 16)     : N_NODES;
        idx[3][0] = (e + 0 < len3) ? (int)(c3.x & 0xFFFFu) : N_NODES;
        idx[3][1] = (e + 1 < len3) ? (int)(c3.x >> 16)     : N_NODES;
        idx[3][2] = (e + 2 < len3) ? (int)(c3.y & 0xFFFFu) : N_NODES;
        idx[3][3] = (e + 3 < len3) ? (int)(c3.y >> 16)     : N_NODES;
        unsigned int uu[4][4];
#pragma unroll
        for (int p = 0; p < 4; ++p)
#pragma unroll
            for (int j = 0; j < 4; ++j)
                uu[p][j] = ui32[(size_t)idx[p][j] * 64 + lane];
#pragma unroll
        for (int p = 0; p < 4; ++p) {
            float2 v0 = h2f2(uu[p][0]), v1 = h2f2(uu[p][1]),
                   v2 = h2f2(uu[p][2]), v3 = h2f2(uu[p][3]);
            ax[p] += (v0.x + v1.x) + (v2.x + v3.x);
            ay[p] += (v0.y + v1.y) + (v2.y + v3.y);
        }
    }
#pragma unroll
    for (int p = 0; p < 4; ++p) {
        float2 xf = h2f2(xu[p]);
        usum[p] = make_float2(ax[p], ay[p]);
        xv[p] = make_float2(fmaxf(xf.x + ax[p], 0.f), fmaxf(xf.y + ay[p], 0.f));
    }
}

// pack two staged _Float16 (same-typed LDS reads -> compiler keeps ds order) into a uint
static __device__ __forceinline__ unsigned int pack_stg(const _Float16* p) {
    union { _Float16 h[2]; unsigned int u; } pk;
    pk.h[0] = p[0];
    pk.h[1] = p[1];
    return pk.u;
}

// ---------------- half-GEMM with LDS-staged FULL-LINE stores (race-fixed) ----------------
// Stage each 16x128 output chunk in x_sm (wave-private rows), then store rows as
// 64-lane x 4B = 256B contiguous writes. Barriers: [A] protects frag loads from staging
// overwrite (cross-wave); [B] orders staging writes vs readback (belt+suspenders; uniform).
static __device__ __forceinline__ void gemm_from_lds_half(
        _Float16 (*x_sm)[136], int band, int hs, int L,
        const _Float16* __restrict__ Bh, const _Float16* __restrict__ Bl,
        const float* __restrict__ bl_, const float* __restrict__ ba_,
        int R0, _Float16* __restrict__ xi16, _Float16* __restrict__ ui16) {
    int m = L & 15, q = L >> 4;
    int Rw = R0 + band * 32;
    int tbase = hs * 8;
    f16x8 a[2][4];
#pragma unroll
    for (int rt = 0; rt < 2; ++rt)
#pragma unroll
        for (int c = 0; c < 4; ++c)
            a[rt][c] = *(const f16x8*)&x_sm[band * 32 + rt * 16 + m][c * 32 + q * 8];
    __syncthreads();   // [A] all frag loads done; x_sm reusable as staging scratch
    _Float16 (*stg)[136] = (_Float16 (*)[136])&x_sm[band * 32 + hs * 16];  // wave-private 16 rows
    unsigned int* dstw = (unsigned int*)(hs ? ui16 : xi16);
    const float* bb = hs ? ba_ : bl_;
#pragma unroll
    for (int rt = 0; rt < 2; ++rt) {
#pragma unroll
        for (int t = 0; t < 8; ++t) {
            int tg = tbase + t;
            f32x4 acc = (f32x4)(0.f);
#pragma unroll
            for (int c = 0; c < 4; ++c) {
                f16x8 bh = *(const f16x8*)&Bh[(size_t)((tg * 4 + c) * 64 + L) * 8];
                f16x8 bl = *(const f16x8*)&Bl[(size_t)((tg * 4 + c) * 64 + L) * 8];
                acc = __builtin_amdgcn_mfma_f32_16x16x32_f16(a[rt][c], bh, acc, 0, 0, 0);
                acc = __builtin_amdgcn_mfma_f32_16x16x32_f16(a[rt][c], bl, acc, 0, 0, 0);
            }
            float bias = bb[t * 16 + m];
#pragma unroll
            for (int r = 0; r < 4; ++r)
                stg[q * 4 + r][t * 16 + m] = (_Float16)(acc[r] + bias);
        }
        __syncthreads();   // [B] staging writes ordered before readback (uniform trip count)
        // coalesced full-line stores: one 256B row per instruction
#pragma unroll
        for (int lr = 0; lr < 16; ++lr)
            dstw[(size_t)(Rw + rt * 16 + lr) * 64 + L] = pack_stg(&stg[lr][L * 2]);
        __builtin_amdgcn_sched_barrier(0);   // pin readback before next rt's overwrite
    }
}

// ---------------- full-GEMM (proj layer-1 path, 4 waves) with the same staged stores ----------------
static __device__ __forceinline__ void gemm_from_lds(
        _Float16 (*x_sm)[136], int wv, int L,
        const _Float16* __restrict__ Bh, const _Float16* __restrict__ Bl,
        const float* __restrict__ bl_, const float* __restrict__ ba_,
        int R0, _Float16* __restrict__ xi16, _Float16* __restrict__ ui16) {
    int m = L & 15, q = L >> 4;
    int Rw = R0 + wv * 32;
    f16x8 a[2][4];
#pragma unroll
    for (int rt = 0; rt < 2; ++rt)
#pragma unroll
        for (int c = 0; c < 4; ++c)
            a[rt][c] = *(const f16x8*)&x_sm[wv * 32 + rt * 16 + m][c * 32 + q * 8];
    __syncthreads();   // [A]
    _Float16 (*stg)[136] = (_Float16 (*)[136])&x_sm[wv * 32];  // wave-private 16-row scratch
#pragma unroll
    for (int half = 0; half < 2; ++half) {
        unsigned int* dstw = (unsigned int*)(half ? ui16 : xi16);
        const float* bb = half ? ba_ : bl_;
#pragma unroll
        for (int rt = 0; rt < 2; ++rt) {
#pragma unroll
            for (int t = 0; t < 8; ++t) {
                int tg = half * 8 + t;
                f32x4 acc = (f32x4)(0.f);
#pragma unroll
                for (int c = 0; c < 4; ++c) {
                    f16x8 bh = *(const f16x8*)&Bh[(size_t)((tg * 4 + c) * 64 + L) * 8];
                    f16x8 bl = *(const f16x8*)&Bl[(size_t)((tg * 4 + c) * 64 + L) * 8];
                    acc = __builtin_amdgcn_mfma_f32_16x16x32_f16(a[rt][c], bh, acc, 0, 0, 0);
                    acc = __builtin_amdgcn_mfma_f32_16x16x32_f16(a[rt][c], bl, acc, 0, 0, 0);
                }
                float bias = bb[t * 16 + m];
#pragma unroll
                for (int r = 0; r < 4; ++r)
                    stg[q * 4 + r][t * 16 + m] = (_Float16)(acc[r] + bias);
            }
            __syncthreads();   // [B] (uniform trip count across all 4 waves)
#pragma unroll
            for (int lr = 0; lr < 16; ++lr)
                dstw[(size_t)(Rw + rt * 16 + lr) * 64 + L] = pack_stg(&stg[lr][L * 2]);
            __builtin_amdgcn_sched_barrier(0);
        }
    }
}

__global__ __launch_bounds__(256, 2) void proj_gemm_kernel(const float* __restrict__ xin,
                                                           const _Float16* __restrict__ BhP, const _Float16* __restrict__ BlP,
                                                           const float* __restrict__ bp,
                                                           const _Float16* __restrict__ Bh1, const _Float16* __restrict__ Bl1,
                                                           const float* __restrict__ bl_, const float* __restrict__ ba_,
                                                           _Float16* __restrict__ xi16, _Float16* __restrict__ ui16) {
    __shared__ __align__(16) _Float16 x_sm[128][136];
    int tid = threadIdx.x;
    int wv = tid >> 6, L = tid & 63;
    int m = L & 15, q = L >> 4;
    int R0 = blockIdx.x * 128;
    int Rw = R0 + wv * 32;
    f16x8 ah[2][2], al[2][2];
#pragma unroll
    for (int rt = 0; rt < 2; ++rt)
#pragma unroll
        for (int c = 0; c < 2; ++c) {
            const float* p = &xin[(size_t)(Rw + rt * 16 + m) * IN_DIM + c * 32 + q * 8];
            float4 f0 = *(const float4*)p;
            float4 f1 = *(const float4*)(p + 4);
            float fv[8] = {f0.x, f0.y, f0.z, f0.w, f1.x, f1.y, f1.z, f1.w};
            f16x8 vh, vl;
#pragma unroll
            for (int j = 0; j < 8; ++j) {
                _Float16 h = (_Float16)fv[j];
                vh[j] = h;
                vl[j] = (_Float16)(fv[j] - (float)h);
            }
            ah[rt][c] = vh;
            al[rt][c] = vl;
        }
#pragma unroll
    for (int t = 0; t < 8; ++t) {
        f32x4 a0 = (f32x4)(0.f), a1 = (f32x4)(0.f);
#pragma unroll
        for (int c = 0; c < 2; ++c) {
            f16x8 bh = *(const f16x8*)&BhP[(size_t)((t * 2 + c) * 64 + L) * 8];
            f16x8 bl = *(const f16x8*)&BlP[(size_t)((t * 2 + c) * 64 + L) * 8];
            a0 = __builtin_amdgcn_mfma_f32_16x16x32_f16(ah[0][c], bh, a0, 0, 0, 0);
            a1 = __builtin_amdgcn_mfma_f32_16x16x32_f16(ah[1][c], bh, a1, 0, 0, 0);
            a0 = __builtin_amdgcn_mfma_f32_16x16x32_f16(ah[0][c], bl, a0, 0, 0, 0);
            a1 = __builtin_amdgcn_mfma_f32_16x16x32_f16(ah[1][c], bl, a1, 0, 0, 0);
            a0 = __builtin_amdgcn_mfma_f32_16x16x32_f16(al[0][c], bh, a0, 0, 0, 0);
            a1 = __builtin_amdgcn_mfma_f32_16x16x32_f16(al[1][c], bh, a1, 0, 0, 0);
        }
        int col = t * 16 + m;
        float bias = bp[col];
#pragma unroll
        for (int r = 0; r < 4; ++r) {
            x_sm[wv * 32 + q * 4 + r][col] = (_Float16)fmaxf(a0[r] + bias, 0.f);
            x_sm[wv * 32 + 16 + q * 4 + r][col] = (_Float16)fmaxf(a1[r] + bias, 0.f);
        }
    }
    __syncthreads();
    gemm_from_lds(x_sm, wv, L, Bh1, Bl1, bl_, ba_, R0, xi16, ui16);
}

// ---------------- fused aggregate + layer GEMM (128 nodes/block, 8 waves, grid 512) ----------------
__global__ __launch_bounds__(512, 4) void agg_gemm_kernel(const int* __restrict__ cnt, const unsigned short* __restrict__ csr,
                                                          const unsigned int* __restrict__ xi_prev,
                                                          const unsigned int* __restrict__ ui_prev,
                                                          const _Float16* __restrict__ Bh, const _Float16* __restrict__ Bl,
                                                          const float* __restrict__ bl_, const float* __restrict__ ba_,
                                                          _Float16* __restrict__ xi16, _Float16* __restrict__ ui16) {
    __shared__ __align__(16) _Float16 x_sm[128][136];
    int tid = threadIdx.x;
    int wv = tid >> 6, lane = tid & 63;
    int R0 = blockIdx.x * 128;
    // aggregate: wave wv owns 16 nodes
    int nb = R0 + wv * 16;
    for (int s = 0; s < 4; ++s) {
        float2 us[4], xv[4];
        agg_block4(nb + s * 4, lane, cnt, csr, xi_prev, ui_prev, us, xv);
#pragma unroll
        for (int p = 0; p < 4; ++p)
            *(unsigned int*)&x_sm[wv * 16 + s * 4 + p][lane * 2] = f2h2(xv[p].x, xv[p].y);
    }
    __syncthreads();
    // GEMM: wave-pair decomposition (band = wv>>1, t-half = wv&1), staged full-line stores
    gemm_from_lds_half(x_sm, wv >> 1, wv & 1, lane, Bh, Bl, bl_, ba_, R0, xi16, ui16);
}

// ---------------- final aggregate (512 threads, 128 nodes/block): x -> global, u_g, BN stats ----------------
__global__ __launch_bounds__(512, 4) void agg_final_kernel(const int* __restrict__ cnt, const unsigned short* __restrict__ csr,
                                                           const unsigned int* __restrict__ xi_prev,
                                                           const unsigned int* __restrict__ ui_prev,
                                                           unsigned int* __restrict__ x32out,
                                                           float* __restrict__ u_g,
                                                           float* __restrict__ sums, float* __restrict__ sq) {
    __shared__ float red[8][64][6];
    int tid = threadIdx.x;
    int wv = tid >> 6, lane = tid & 63;
    int nb = blockIdx.x * 128 + wv * 16;
    float gx = 0.f, gy = 0.f, s0 = 0.f, s1 = 0.f, q0 = 0.f, q1 = 0.f;
    for (int s = 0; s < 4; ++s) {
        float2 us[4], xv[4];
        agg_block4(nb + s * 4, lane, cnt, csr, xi_prev, ui_prev, us, xv);
#pragma unroll
        for (int p = 0; p < 4; ++p) {
            x32out[(size_t)(nb + s * 4 + p) * 64 + lane] = f2h2(xv[p].x, xv[p].y);
            gx += us[p].x; gy += us[p].y;
            s0 += xv[p].x; s1 += xv[p].y;
            q0 += xv[p].x * xv[p].x; q1 += xv[p].y * xv[p].y;
        }
    }
    red[wv][lane][0] = gx; red[wv][lane][1] = gy;
    red[wv][lane][2] = s0; red[wv][lane][3] = s1;
    red[wv][lane][4] = q0; red[wv][lane][5] = q1;
    __syncthreads();
    if (tid < 64) {
        int t = tid;
        float G0 = 0.f, G1 = 0.f, S0 = 0.f, S1 = 0.f, Q0 = 0.f, Q1 = 0.f;
#pragma unroll
        for (int w = 0; w < 8; ++w) {
            G0 += red[w][t][0]; G1 += red[w][t][1];
            S0 += red[w][t][2]; S1 += red[w][t][3];
            Q0 += red[w][t][4]; Q1 += red[w][t][5];
        }
        int g = blockIdx.x >> 3;   // 128 nodes/block, 8 blocks/graph
        atomicAdd(&u_g[g * HID + t * 2], G0);
        atomicAdd(&u_g[g * HID + t * 2 + 1], G1);
        atomicAdd(&sums[t * 2], S0);
        atomicAdd(&sums[t * 2 + 1], S1);
        atomicAdd(&sq[t * 2], Q0);
        atomicAdd(&sq[t * 2 + 1], Q1);
    }
}

// ---------------- finalize: BN coefs P, const, per-graph S ----------------
__global__ __launch_bounds__(256) void finalize_kernel(const float* __restrict__ sums, const float* __restrict__ sq,
                                                       const float* __restrict__ u_g,
                                                       const float* __restrict__ gamma, const float* __restrict__ beta,
                                                       const float* __restrict__ Wf, const float* __restrict__ bf,
                                                       float* __restrict__ P, float* __restrict__ constv,
                                                       float* __restrict__ S) {
    __shared__ float red0[256], red1[256];
    int c = threadIdx.x;
    float mean, var;
    if (c < HID) {
        mean = sums[c] * (1.f / N_NODES);
        var = sq[c] * (1.f / N_NODES) - mean * mean;
    } else {
        int d = c - HID;
        float s = 0.f, s2 = 0.f;
        for (int g = 0; g < NGRAPH; ++g) {
            float v = u_g[g * HID + d];
            s += v; s2 += v * v;
        }
        mean = s * (1.f / NGRAPH);
        var = s2 * (1.f / NGRAPH) - mean * mean;
    }
    float a = gamma[c] * rsqrtf(var + EPS);
    float bsh = beta[c] - mean * a;
    float w0 = Wf[c * 2], w1 = Wf[c * 2 + 1];
    P[c * 2] = a * w0;
    P[c * 2 + 1] = a * w1;
    red0[c] = bsh * w0;
    red1[c] = bsh * w1;
    __syncthreads();
    for (int off = 128; off > 0; off >>= 1) {
        if (c < off) { red0[c] += red0[c + off]; red1[c] += red1[c + off]; }
        __syncthreads();
    }
    if (c == 0) {
        constv[0] = bf[0] + red0[0];
        constv[1] = bf[1] + red1[0];
    }
    __syncthreads();
    if (c < NGRAPH * 2) {
        int g = c >> 1, j = c & 1;
        float s = 0.f;
        for (int d = 0; d < HID; ++d) s += u_g[g * HID + d] * P[(HID + d) * 2 + j];
        S[g * 2 + j] = s;
    }
}

// ---------------- final: out[n][j] = sum_c x[n][c]*P[c][j] + S[g][j] + const[j] ----------------
__global__ __launch_bounds__(256) void final_kernel(const unsigned int* __restrict__ x32,
                                                    const float* __restrict__ P,
                                                    const float* __restrict__ S, const float* __restrict__ constv,
                                                    float* __restrict__ out) {
    int tid = threadIdx.x;
    int row = blockIdx.x * 4 + (tid >> 6);
    int lane = tid & 63;
    float2 v = h2f2(x32[(size_t)row * 64 + lane]);
    float4 p = *(const float4*)&P[lane * 4];
    float a0 = v.x * p.x + v.y * p.z;
    float a1 = v.x * p.y + v.y * p.w;
#pragma unroll
    for (int off = 32; off > 0; off >>= 1) {
        a0 += __shfl_down(a0, off);
        a1 += __shfl_down(a1, off);
    }
    if (lane == 0) {
        int g = row >> 10;
        float2 o;
        o.x = a0 + S[g * 2] + constv[0];
        o.y = a1 + S[g * 2 + 1] + constv[1];
        *(float2*)&out[(size_t)row * 2] = o;
    }
}

extern "C" void kernel_launch(void* const* d_in, const int* in_sizes, int n_in,
                              void* d_out, int out_size, void* d_ws, size_t ws_size,
                              hipStream_t stream) {
    const float* x_in   = (const float*)d_in[0];
    const int*   ei     = (const int*)d_in[1];
    const float* W_proj = (const float*)d_in[3];
    const float* b_proj = (const float*)d_in[4];
    const float* W_lay  = (const float*)d_in[5];
    const float* b_lay  = (const float*)d_in[6];
    const float* W_aggr = (const float*)d_in[7];
    const float* b_aggr = (const float*)d_in[8];
    const float* gamma  = (const float*)d_in[9];
    const float* beta   = (const float*)d_in[10];
    const float* W_fin  = (const float*)d_in[11];
    const float* b_fin  = (const float*)d_in[12];
    float* out = (float*)d_out;

    const int* src = ei;
    const int* dst = ei + N_EDGES;

    const size_t NM = (size_t)N_NODES * HID;
    _Float16* xiA = (_Float16*)d_ws;           // 16MB
    _Float16* uiA = xiA + NM;                  // 16MB + dummy row
    _Float16* xiB = uiA + NM + HID;            // 16MB
    _Float16* uiB = xiB + NM;                  // 16MB + dummy row
    _Float16* xF  = uiB + NM + HID;            // 16MB (final x for BN/final)
    _Float16* BhL = xF + NM;                   // 98304
    _Float16* BlL = BhL + 98304;
    _Float16* BhP = BlL + 98304;               // 8192
    _Float16* BlP = BhP + 8192;
    int* cnt = (int*)(BlP + 8192);             // 65536 ints
    unsigned short* csr = (unsigned short*)(cnt + N_NODES);  // 65536*64 ushort (8.4MB)
    float* u_g    = (float*)(csr + (size_t)N_NODES * CAP);   // 8192
    float* sums   = u_g + NGRAPH * HID;        // 128
    float* sq     = sums + HID;                // 128
    float* P      = sq + HID;                  // 512
    float* constv = P + 512;                   // 2
    float* S      = constv + 2;                // 128

    hipMemsetAsync(cnt, 0, (size_t)N_NODES * sizeof(int), stream);
    hipMemsetAsync(u_g, 0, (size_t)(NGRAPH * HID + 2 * HID) * sizeof(float), stream);

    fillcsr_kernel<<<N_EDGES / 256, 256, 0, stream>>>(src, dst, cnt, csr,
                                                      (unsigned int*)(uiA + NM),
                                                      (unsigned int*)(uiB + NM));

    pack_kernel<<<52, 256, 0, stream>>>(W_lay, W_aggr, W_proj, BhL, BlL, BhP, BlP);

    // layer 1: proj (LDS) + GEMM1 -> xiA/uiA
    proj_gemm_kernel<<<N_NODES / 128, 256, 0, stream>>>(
        x_in, BhP, BlP, b_proj,
        BhL, BlL, b_lay, b_aggr, xiA, uiA);

    // layer 2: aggregate(uiA)+xiA (LDS) + GEMM2 -> xiB/uiB
    agg_gemm_kernel<<<N_NODES / 128, 512, 0, stream>>>(
        cnt, csr, (const unsigned int*)xiA, (const unsigned int*)uiA,
        BhL + (size_t)1 * 4096 * 8, BlL + (size_t)1 * 4096 * 8,
        b_lay + HID, b_aggr + HID, xiB, uiB);

    // layer 3: aggregate(uiB)+xiB (LDS) + GEMM3 -> xiA/uiA
    agg_gemm_kernel<<<N_NODES / 128, 512, 0, stream>>>(
        cnt, csr, (const unsigned int*)xiB, (const unsigned int*)uiB,
        BhL + (size_t)2 * 4096 * 8, BlL + (size_t)2 * 4096 * 8,
        b_lay + 2 * HID, b_aggr + 2 * HID, xiA, uiA);

    // final aggregate: x -> xF, u_g accum, fused BN column stats
    agg_final_kernel<<<N_NODES / 128, 512, 0, stream>>>(
        cnt, csr, (const unsigned int*)xiA, (const unsigned int*)uiA,
        (unsigned int*)xF, u_g, sums, sq);

    finalize_kernel<<<1, 256, 0, stream>>>(sums, sq, u_g, gamma, beta, W_fin, b_fin, P, constv, S);
    final_kernel<<<N_NODES / 4, 256, 0, stream>>>((const unsigned int*)xF, P, S, constv, out);
}

// Round 8
// 304.158 us; speedup vs baseline: 1.1160x; 1.0335x over previous
//
#include <hip/hip_runtime.h>
#include <hip/hip_fp16.h>

#define N_NODES   65536
#define N_EDGES   524288
#define IN_DIM    64
#define HID       128
#define NPG       1024
#define NGRAPH    64
#define EPS       1e-5f
#define CAP       64   // bucket capacity per node (Poisson(8) tail << 64)

typedef __attribute__((ext_vector_type(8))) _Float16 f16x8;
typedef __attribute__((ext_vector_type(4))) float f32x4;

// packed fp16 pair <-> float2
static __device__ __forceinline__ float2 h2f2(unsigned int u) {
    union { unsigned int u; __half2 h; } cv;
    cv.u = u;
    return __half22float2(cv.h);
}
static __device__ __forceinline__ unsigned int f2h2(float a, float b) {
    union { __half2 h; unsigned int u; } cv;
    cv.h = __floats2half2_rn(a, b);
    return cv.u;
}

// ---------------- bucket-CSR build (ushort payload); also zeroes both ui dummy rows ----------------
__global__ __launch_bounds__(256) void fillcsr_kernel(const int* __restrict__ src, const int* __restrict__ dst,
                                                      int* __restrict__ cnt, unsigned short* __restrict__ csr,
                                                      unsigned int* __restrict__ dummyA,
                                                      unsigned int* __restrict__ dummyB) {
    if (blockIdx.x == 0) {
        if (threadIdx.x < 64) dummyA[threadIdx.x] = 0u;
        else if (threadIdx.x < 128) dummyB[threadIdx.x - 64] = 0u;
    }
    int e = blockIdx.x * 256 + threadIdx.x;
    if (e < N_EDGES) {
        int d = dst[e];
        int slot = atomicAdd(&cnt[d], 1);
        if (slot < CAP) csr[(size_t)d * CAP + slot] = (unsigned short)src[e];
    }
}

// ---------------- weight prepack: split fp16 (hi+lo) in MFMA B-fragment order ----------------
__global__ __launch_bounds__(256) void pack_kernel(const float* __restrict__ Wl, const float* __restrict__ Wa,
                                                   const float* __restrict__ Wp,
                                                   _Float16* __restrict__ BhL, _Float16* __restrict__ BlL,
                                                   _Float16* __restrict__ BhP, _Float16* __restrict__ BlP) {
    int id = blockIdx.x * 256 + threadIdx.x;
    if (id < 12288) {
        int L = id & 63, c = (id >> 6) & 3, t = (id >> 8) & 15, i = id >> 12;
        int n = t * 16 + (L & 15);
        int k0 = c * 32 + ((L >> 4) * 8);
        const float* W = (n < HID) ? (Wl + (size_t)i * HID * HID + n)
                                   : (Wa + (size_t)i * HID * HID + (n - HID));
        f16x8 vh, vl;
#pragma unroll
        for (int j = 0; j < 8; ++j) {
            float w = W[(size_t)(k0 + j) * HID];
            _Float16 h = (_Float16)w;
            vh[j] = h;
            vl[j] = (_Float16)(w - (float)h);
        }
        *(f16x8*)&BhL[(size_t)id * 8] = vh;
        *(f16x8*)&BlL[(size_t)id * 8] = vl;
    } else if (id < 12288 + 1024) {
        int p = id - 12288;
        int L = p & 63, c = (p >> 6) & 1, t = (p >> 7) & 7;
        int n = t * 16 + (L & 15);
        int k0 = c * 32 + ((L >> 4) * 8);
        f16x8 vh, vl;
#pragma unroll
        for (int j = 0; j < 8; ++j) {
            float w = Wp[(size_t)(k0 + j) * HID + n];
            _Float16 h = (_Float16)w;
            vh[j] = h;
            vl[j] = (_Float16)(w - (float)h);
        }
        *(f16x8*)&BhP[(size_t)p * 8] = vh;
        *(f16x8*)&BlP[(size_t)p * 8] = vl;
    }
}

// ---------------- shared: aggregate 4 nodes (one wave-lane slice, 2 cols/lane) ----------------
static __device__ __forceinline__ void agg_block4(
        int nbase, int lane,
        const int* __restrict__ cnt, const unsigned short* __restrict__ csr,
        const unsigned int* __restrict__ xi32, const unsigned int* __restrict__ ui32,
        float2* __restrict__ usum, float2* __restrict__ xv) {
    int4 c4 = *(const int4*)&cnt[nbase];
    int len0 = min(c4.x, CAP), len1 = min(c4.y, CAP),
        len2 = min(c4.z, CAP), len3 = min(c4.w, CAP);
    int maxlen = max(max(len0, len1), max(len2, len3));
    unsigned int xu[4];
#pragma unroll
    for (int p = 0; p < 4; ++p) xu[p] = xi32[(size_t)(nbase + p) * 64 + lane];
    float ax[4] = {0.f, 0.f, 0.f, 0.f}, ay[4] = {0.f, 0.f, 0.f, 0.f};
    size_t eb = (size_t)nbase * CAP;
    for (int e = 0; e < maxlen; e += 4) {
        uint2 c0 = *(const uint2*)&csr[eb + 0 * CAP + e];
        uint2 c1 = *(const uint2*)&csr[eb + 1 * CAP + e];
        uint2 c2 = *(const uint2*)&csr[eb + 2 * CAP + e];
        uint2 c3 = *(const uint2*)&csr[eb + 3 * CAP + e];
        int idx[4][4];
        idx[0][0] = (e + 0 < len0) ? (int)(c0.x & 0xFFFFu) : N_NODES;
        idx[0][1] = (e + 1 < len0) ? (int)(c0.x >> 16)     : N_NODES;
        idx[0][2] = (e + 2 < len0) ? (int)(c0.y & 0xFFFFu) : N_NODES;
        idx[0][3] = (e + 3 < len0) ? (int)(c0.y >> 16)     : N_NODES;
        idx[1][0] = (e + 0 < len1) ? (int)(c1.x & 0xFFFFu) : N_NODES;
        idx[1][1] = (e + 1 < len1) ? (int)(c1.x >> 16)     : N_NODES;
        idx[1][2] = (e + 2 < len1) ? (int)(c1.y & 0xFFFFu) : N_NODES;
        idx[1][3] = (e + 3 < len1) ? (int)(c1.y >> 16)     : N_NODES;
        idx[2][0] = (e + 0 < len2) ? (int)(c2.x & 0xFFFFu) : N_NODES;
        idx[2][1] = (e + 1 < len2) ? (int)(c2.x >> 16)     : N_NODES;
        idx[2][2] = (e + 2 < len2) ? (int)(c2.y & 0xFFFFu) : N_NODES;
        idx[2][3] = (e + 3 < len2) ? (int)(c2.y >> 16)     : N_NODES;
        idx[3][0] = (e + 0 < len3) ? (int)(c3.x & 0xFFFFu) : N_NODES;
        idx[3][1] = (e + 1 < len3) ? (int)(c3.x >> 16)     : N_NODES;
        idx[3][2] = (e + 2 < len3) ? (int)(c3.y & 0xFFFFu) : N_NODES;
        idx[3][3] = (e + 3 < len3) ? (int)(c3.y >> 16)     : N_NODES;
        unsigned int uu[4][4];
#pragma unroll
        for (int p = 0; p < 4; ++p)
#pragma unroll
            for (int j = 0; j < 4; ++j)
                uu[p][j] = ui32[(size_t)idx[p][j] * 64 + lane];
#pragma unroll
        for (int p = 0; p < 4; ++p) {
            float2 v0 = h2f2(uu[p][0]), v1 = h2f2(uu[p][1]),
                   v2 = h2f2(uu[p][2]), v3 = h2f2(uu[p][3]);
            ax[p] += (v0.x + v1.x) + (v2.x + v3.x);
            ay[p] += (v0.y + v1.y) + (v2.y + v3.y);
        }
    }
#pragma unroll
    for (int p = 0; p < 4; ++p) {
        float2 xf = h2f2(xu[p]);
        usum[p] = make_float2(ax[p], ay[p]);
        xv[p] = make_float2(fmaxf(xf.x + ax[p], 0.f), fmaxf(xf.y + ay[p], 0.f));
    }
}

// ---------------- shared: half-GEMM (8 t-tiles) for one 32-row band, A in LDS ----------------
static __device__ __forceinline__ void gemm_from_lds_half(
        const _Float16 (*x_sm)[136], int band, int tbase, int L,
        const _Float16* __restrict__ Bh, const _Float16* __restrict__ Bl,
        const float* __restrict__ bl_, const float* __restrict__ ba_,
        int R0, _Float16* __restrict__ xi16, _Float16* __restrict__ ui16) {
    int m = L & 15, q = L >> 4;
    int Rw = R0 + band * 32;
    f16x8 a[2][4];
#pragma unroll
    for (int rt = 0; rt < 2; ++rt)
#pragma unroll
        for (int c = 0; c < 4; ++c)
            a[rt][c] = *(const f16x8*)&x_sm[band * 32 + rt * 16 + m][c * 32 + q * 8];
    // tbase==0 -> xi half; tbase==8 -> ui half (wave-uniform)
    _Float16* dstp = tbase ? ui16 : xi16;
    const float* bb = tbase ? ba_ : bl_;
#pragma unroll
    for (int t = 0; t < 8; ++t) {
        int tg = tbase + t;
        f32x4 a0 = (f32x4)(0.f), a1 = (f32x4)(0.f);
#pragma unroll
        for (int c = 0; c < 4; ++c) {
            f16x8 bh = *(const f16x8*)&Bh[(size_t)((tg * 4 + c) * 64 + L) * 8];
            f16x8 bl = *(const f16x8*)&Bl[(size_t)((tg * 4 + c) * 64 + L) * 8];
            a0 = __builtin_amdgcn_mfma_f32_16x16x32_f16(a[0][c], bh, a0, 0, 0, 0);
            a1 = __builtin_amdgcn_mfma_f32_16x16x32_f16(a[1][c], bh, a1, 0, 0, 0);
            a0 = __builtin_amdgcn_mfma_f32_16x16x32_f16(a[0][c], bl, a0, 0, 0, 0);
            a1 = __builtin_amdgcn_mfma_f32_16x16x32_f16(a[1][c], bl, a1, 0, 0, 0);
        }
        int dc = t * 16 + m;
        float bias = bb[dc];
#pragma unroll
        for (int r = 0; r < 4; ++r) {
            dstp[(size_t)(Rw + q * 4 + r) * HID + dc] = (_Float16)(a0[r] + bias);
            dstp[(size_t)(Rw + 16 + q * 4 + r) * HID + dc] = (_Float16)(a1[r] + bias);
        }
    }
}

// ---------------- fused proj + layer-1 GEMM (256 threads; not latency-bound) ----------------
static __device__ __forceinline__ void gemm_from_lds(
        const _Float16 (*x_sm)[136], int wv, int L,
        const _Float16* __restrict__ Bh, const _Float16* __restrict__ Bl,
        const float* __restrict__ bl_, const float* __restrict__ ba_,
        int R0, _Float16* __restrict__ xi16, _Float16* __restrict__ ui16) {
    int m = L & 15, q = L >> 4;
    int Rw = R0 + wv * 32;
    f16x8 a[2][4];
#pragma unroll
    for (int rt = 0; rt < 2; ++rt)
#pragma unroll
        for (int c = 0; c < 4; ++c)
            a[rt][c] = *(const f16x8*)&x_sm[wv * 32 + rt * 16 + m][c * 32 + q * 8];
#pragma unroll
    for (int t = 0; t < 16; ++t) {
        f32x4 a0 = (f32x4)(0.f), a1 = (f32x4)(0.f);
#pragma unroll
        for (int c = 0; c < 4; ++c) {
            f16x8 bh = *(const f16x8*)&Bh[(size_t)((t * 4 + c) * 64 + L) * 8];
            f16x8 bl = *(const f16x8*)&Bl[(size_t)((t * 4 + c) * 64 + L) * 8];
            a0 = __builtin_amdgcn_mfma_f32_16x16x32_f16(a[0][c], bh, a0, 0, 0, 0);
            a1 = __builtin_amdgcn_mfma_f32_16x16x32_f16(a[1][c], bh, a1, 0, 0, 0);
            a0 = __builtin_amdgcn_mfma_f32_16x16x32_f16(a[0][c], bl, a0, 0, 0, 0);
            a1 = __builtin_amdgcn_mfma_f32_16x16x32_f16(a[1][c], bl, a1, 0, 0, 0);
        }
        int col = t * 16 + m;
        float bias = (t < 8) ? bl_[col] : ba_[col - HID];
        _Float16* dstp = (t < 8) ? xi16 : ui16;
        int dc = (t < 8) ? col : col - HID;
#pragma unroll
        for (int r = 0; r < 4; ++r) {
            dstp[(size_t)(Rw + q * 4 + r) * HID + dc] = (_Float16)(a0[r] + bias);
            dstp[(size_t)(Rw + 16 + q * 4 + r) * HID + dc] = (_Float16)(a1[r] + bias);
        }
    }
}

__global__ __launch_bounds__(256, 2) void proj_gemm_kernel(const float* __restrict__ xin,
                                                           const _Float16* __restrict__ BhP, const _Float16* __restrict__ BlP,
                                                           const float* __restrict__ bp,
                                                           const _Float16* __restrict__ Bh1, const _Float16* __restrict__ Bl1,
                                                           const float* __restrict__ bl_, const float* __restrict__ ba_,
                                                           _Float16* __restrict__ xi16, _Float16* __restrict__ ui16) {
    __shared__ __align__(16) _Float16 x_sm[128][136];
    int tid = threadIdx.x;
    int wv = tid >> 6, L = tid & 63;
    int m = L & 15, q = L >> 4;
    int R0 = blockIdx.x * 128;
    int Rw = R0 + wv * 32;
    f16x8 ah[2][2], al[2][2];
#pragma unroll
    for (int rt = 0; rt < 2; ++rt)
#pragma unroll
        for (int c = 0; c < 2; ++c) {
            const float* p = &xin[(size_t)(Rw + rt * 16 + m) * IN_DIM + c * 32 + q * 8];
            float4 f0 = *(const float4*)p;
            float4 f1 = *(const float4*)(p + 4);
            float fv[8] = {f0.x, f0.y, f0.z, f0.w, f1.x, f1.y, f1.z, f1.w};
            f16x8 vh, vl;
#pragma unroll
            for (int j = 0; j < 8; ++j) {
                _Float16 h = (_Float16)fv[j];
                vh[j] = h;
                vl[j] = (_Float16)(fv[j] - (float)h);
            }
            ah[rt][c] = vh;
            al[rt][c] = vl;
        }
#pragma unroll
    for (int t = 0; t < 8; ++t) {
        f32x4 a0 = (f32x4)(0.f), a1 = (f32x4)(0.f);
#pragma unroll
        for (int c = 0; c < 2; ++c) {
            f16x8 bh = *(const f16x8*)&BhP[(size_t)((t * 2 + c) * 64 + L) * 8];
            f16x8 bl = *(const f16x8*)&BlP[(size_t)((t * 2 + c) * 64 + L) * 8];
            a0 = __builtin_amdgcn_mfma_f32_16x16x32_f16(ah[0][c], bh, a0, 0, 0, 0);
            a1 = __builtin_amdgcn_mfma_f32_16x16x32_f16(ah[1][c], bh, a1, 0, 0, 0);
            a0 = __builtin_amdgcn_mfma_f32_16x16x32_f16(ah[0][c], bl, a0, 0, 0, 0);
            a1 = __builtin_amdgcn_mfma_f32_16x16x32_f16(ah[1][c], bl, a1, 0, 0, 0);
            a0 = __builtin_amdgcn_mfma_f32_16x16x32_f16(al[0][c], bh, a0, 0, 0, 0);
            a1 = __builtin_amdgcn_mfma_f32_16x16x32_f16(al[1][c], bh, a1, 0, 0, 0);
        }
        int col = t * 16 + m;
        float bias = bp[col];
#pragma unroll
        for (int r = 0; r < 4; ++r) {
            x_sm[wv * 32 + q * 4 + r][col] = (_Float16)fmaxf(a0[r] + bias, 0.f);
            x_sm[wv * 32 + 16 + q * 4 + r][col] = (_Float16)fmaxf(a1[r] + bias, 0.f);
        }
    }
    __syncthreads();
    gemm_from_lds(x_sm, wv, L, Bh1, Bl1, bl_, ba_, R0, xi16, ui16);
}

// ---------------- fused aggregate + layer GEMM (512 threads: 8 waves for latency hiding) ----------------
__global__ __launch_bounds__(512, 4) void agg_gemm_kernel(const int* __restrict__ cnt, const unsigned short* __restrict__ csr,
                                                          const unsigned int* __restrict__ xi_prev,
                                                          const unsigned int* __restrict__ ui_prev,
                                                          const _Float16* __restrict__ Bh, const _Float16* __restrict__ Bl,
                                                          const float* __restrict__ bl_, const float* __restrict__ ba_,
                                                          _Float16* __restrict__ xi16, _Float16* __restrict__ ui16) {
    __shared__ __align__(16) _Float16 x_sm[128][136];
    int tid = threadIdx.x;
    int wv = tid >> 6, lane = tid & 63;
    int R0 = blockIdx.x * 128;
    // aggregate: wave wv owns 16 nodes
    int nb = R0 + wv * 16;
    for (int s = 0; s < 4; ++s) {
        float2 us[4], xv[4];
        agg_block4(nb + s * 4, lane, cnt, csr, xi_prev, ui_prev, us, xv);
#pragma unroll
        for (int p = 0; p < 4; ++p)
            *(unsigned int*)&x_sm[wv * 16 + s * 4 + p][lane * 2] = f2h2(xv[p].x, xv[p].y);
    }
    __syncthreads();
    // GEMM: wave-pair decomposition (band = wv>>1, t-half = wv&1)
    gemm_from_lds_half(x_sm, wv >> 1, (wv & 1) * 8, lane, Bh, Bl, bl_, ba_, R0, xi16, ui16);
}

// ---------------- final aggregate (512 threads): x -> global, u_g accum, BN column stats ----------------
__global__ __launch_bounds__(512, 4) void agg_final_kernel(const int* __restrict__ cnt, const unsigned short* __restrict__ csr,
                                                           const unsigned int* __restrict__ xi_prev,
                                                           const unsigned int* __restrict__ ui_prev,
                                                           unsigned int* __restrict__ x32out,
                                                           float* __restrict__ u_g,
                                                           float* __restrict__ sums, float* __restrict__ sq) {
    __shared__ float red[8][64][6];
    int tid = threadIdx.x;
    int wv = tid >> 6, lane = tid & 63;
    int nb = blockIdx.x * 128 + wv * 16;
    float gx = 0.f, gy = 0.f, s0 = 0.f, s1 = 0.f, q0 = 0.f, q1 = 0.f;
    for (int s = 0; s < 4; ++s) {
        float2 us[4], xv[4];
        agg_block4(nb + s * 4, lane, cnt, csr, xi_prev, ui_prev, us, xv);
#pragma unroll
        for (int p = 0; p < 4; ++p) {
            x32out[(size_t)(nb + s * 4 + p) * 64 + lane] = f2h2(xv[p].x, xv[p].y);
            gx += us[p].x; gy += us[p].y;
            s0 += xv[p].x; s1 += xv[p].y;
            q0 += xv[p].x * xv[p].x; q1 += xv[p].y * xv[p].y;
        }
    }
    red[wv][lane][0] = gx; red[wv][lane][1] = gy;
    red[wv][lane][2] = s0; red[wv][lane][3] = s1;
    red[wv][lane][4] = q0; red[wv][lane][5] = q1;
    __syncthreads();
    if (tid < 64) {
        int t = tid;
        float G0 = 0.f, G1 = 0.f, S0 = 0.f, S1 = 0.f, Q0 = 0.f, Q1 = 0.f;
#pragma unroll
        for (int w = 0; w < 8; ++w) {
            G0 += red[w][t][0]; G1 += red[w][t][1];
            S0 += red[w][t][2]; S1 += red[w][t][3];
            Q0 += red[w][t][4]; Q1 += red[w][t][5];
        }
        int g = blockIdx.x >> 3;   // 128 nodes/block, 8 blocks/graph
        atomicAdd(&u_g[g * HID + t * 2], G0);
        atomicAdd(&u_g[g * HID + t * 2 + 1], G1);
        atomicAdd(&sums[t * 2], S0);
        atomicAdd(&sums[t * 2 + 1], S1);
        atomicAdd(&sq[t * 2], Q0);
        atomicAdd(&sq[t * 2 + 1], Q1);
    }
}

// ---------------- finalize: BN coefs P, const, per-graph S ----------------
__global__ __launch_bounds__(256) void finalize_kernel(const float* __restrict__ sums, const float* __restrict__ sq,
                                                       const float* __restrict__ u_g,
                                                       const float* __restrict__ gamma, const float* __restrict__ beta,
                                                       const float* __restrict__ Wf, const float* __restrict__ bf,
                                                       float* __restrict__ P, float* __restrict__ constv,
                                                       float* __restrict__ S) {
    __shared__ float red0[256], red1[256];
    int c = threadIdx.x;
    float mean, var;
    if (c < HID) {
        mean = sums[c] * (1.f / N_NODES);
        var = sq[c] * (1.f / N_NODES) - mean * mean;
    } else {
        int d = c - HID;
        float s = 0.f, s2 = 0.f;
        for (int g = 0; g < NGRAPH; ++g) {
            float v = u_g[g * HID + d];
            s += v; s2 += v * v;
        }
        mean = s * (1.f / NGRAPH);
        var = s2 * (1.f / NGRAPH) - mean * mean;
    }
    float a = gamma[c] * rsqrtf(var + EPS);
    float bsh = beta[c] - mean * a;
    float w0 = Wf[c * 2], w1 = Wf[c * 2 + 1];
    P[c * 2] = a * w0;
    P[c * 2 + 1] = a * w1;
    red0[c] = bsh * w0;
    red1[c] = bsh * w1;
    __syncthreads();
    for (int off = 128; off > 0; off >>= 1) {
        if (c < off) { red0[c] += red0[c + off]; red1[c] += red1[c + off]; }
        __syncthreads();
    }
    if (c == 0) {
        constv[0] = bf[0] + red0[0];
        constv[1] = bf[1] + red1[0];
    }
    __syncthreads();
    if (c < NGRAPH * 2) {
        int g = c >> 1, j = c & 1;
        float s = 0.f;
        for (int d = 0; d < HID; ++d) s += u_g[g * HID + d] * P[(HID + d) * 2 + j];
        S[g * 2 + j] = s;
    }
}

// ---------------- final: out[n][j] = sum_c x[n][c]*P[c][j] + S[g][j] + const[j] ----------------
__global__ __launch_bounds__(256) void final_kernel(const unsigned int* __restrict__ x32,
                                                    const float* __restrict__ P,
                                                    const float* __restrict__ S, const float* __restrict__ constv,
                                                    float* __restrict__ out) {
    int tid = threadIdx.x;
    int row = blockIdx.x * 4 + (tid >> 6);
    int lane = tid & 63;
    float2 v = h2f2(x32[(size_t)row * 64 + lane]);
    float4 p = *(const float4*)&P[lane * 4];
    float a0 = v.x * p.x + v.y * p.z;
    float a1 = v.x * p.y + v.y * p.w;
#pragma unroll
    for (int off = 32; off > 0; off >>= 1) {
        a0 += __shfl_down(a0, off);
        a1 += __shfl_down(a1, off);
    }
    if (lane == 0) {
        int g = row >> 10;
        float2 o;
        o.x = a0 + S[g * 2] + constv[0];
        o.y = a1 + S[g * 2 + 1] + constv[1];
        *(float2*)&out[(size_t)row * 2] = o;
    }
}

extern "C" void kernel_launch(void* const* d_in, const int* in_sizes, int n_in,
                              void* d_out, int out_size, void* d_ws, size_t ws_size,
                              hipStream_t stream) {
    const float* x_in   = (const float*)d_in[0];
    const int*   ei     = (const int*)d_in[1];
    const float* W_proj = (const float*)d_in[3];
    const float* b_proj = (const float*)d_in[4];
    const float* W_lay  = (const float*)d_in[5];
    const float* b_lay  = (const float*)d_in[6];
    const float* W_aggr = (const float*)d_in[7];
    const float* b_aggr = (const float*)d_in[8];
    const float* gamma  = (const float*)d_in[9];
    const float* beta   = (const float*)d_in[10];
    const float* W_fin  = (const float*)d_in[11];
    const float* b_fin  = (const float*)d_in[12];
    float* out = (float*)d_out;

    const int* src = ei;
    const int* dst = ei + N_EDGES;

    const size_t NM = (size_t)N_NODES * HID;
    _Float16* xiA = (_Float16*)d_ws;           // 16MB
    _Float16* uiA = xiA + NM;                  // 16MB + dummy row
    _Float16* xiB = uiA + NM + HID;            // 16MB
    _Float16* uiB = xiB + NM;                  // 16MB + dummy row
    _Float16* xF  = uiB + NM + HID;            // 16MB (final x for BN/final)
    _Float16* BhL = xF + NM;                   // 98304
    _Float16* BlL = BhL + 98304;
    _Float16* BhP = BlL + 98304;               // 8192
    _Float16* BlP = BhP + 8192;
    int* cnt = (int*)(BlP + 8192);             // 65536 ints
    unsigned short* csr = (unsigned short*)(cnt + N_NODES);  // 65536*64 ushort (8.4MB)
    float* u_g    = (float*)(csr + (size_t)N_NODES * CAP);   // 8192
    float* sums   = u_g + NGRAPH * HID;        // 128
    float* sq     = sums + HID;                // 128
    float* P      = sq + HID;                  // 512
    float* constv = P + 512;                   // 2
    float* S      = constv + 2;                // 128

    hipMemsetAsync(cnt, 0, (size_t)N_NODES * sizeof(int), stream);
    hipMemsetAsync(u_g, 0, (size_t)(NGRAPH * HID + 2 * HID) * sizeof(float), stream);

    fillcsr_kernel<<<N_EDGES / 256, 256, 0, stream>>>(src, dst, cnt, csr,
                                                      (unsigned int*)(uiA + NM),
                                                      (unsigned int*)(uiB + NM));

    pack_kernel<<<52, 256, 0, stream>>>(W_lay, W_aggr, W_proj, BhL, BlL, BhP, BlP);

    // layer 1: proj (LDS) + GEMM1 -> xiA/uiA
    proj_gemm_kernel<<<N_NODES / 128, 256, 0, stream>>>(
        x_in, BhP, BlP, b_proj,
        BhL, BlL, b_lay, b_aggr, xiA, uiA);

    // layer 2: aggregate(uiA)+xiA (LDS) + GEMM2 -> xiB/uiB
    agg_gemm_kernel<<<N_NODES / 128, 512, 0, stream>>>(
        cnt, csr, (const unsigned int*)xiA, (const unsigned int*)uiA,
        BhL + (size_t)1 * 4096 * 8, BlL + (size_t)1 * 4096 * 8,
        b_lay + HID, b_aggr + HID, xiB, uiB);

    // layer 3: aggregate(uiB)+xiB (LDS) + GEMM3 -> xiA/uiA
    agg_gemm_kernel<<<N_NODES / 128, 512, 0, stream>>>(
        cnt, csr, (const unsigned int*)xiB, (const unsigned int*)uiB,
        BhL + (size_t)2 * 4096 * 8, BlL + (size_t)2 * 4096 * 8,
        b_lay + 2 * HID, b_aggr + 2 * HID, xiA, uiA);

    // final aggregate: x -> xF, u_g accum, fused BN column stats
    agg_final_kernel<<<N_NODES / 128, 512, 0, stream>>>(
        cnt, csr, (const unsigned int*)xiA, (const unsigned int*)uiA,
        (unsigned int*)xF, u_g, sums, sq);

    finalize_kernel<<<1, 256, 0, stream>>>(sums, sq, u_g, gamma, beta, W_fin, b_fin, P, constv, S);
    final_kernel<<<N_NODES / 4, 256, 0, stream>>>((const unsigned int*)xF, P, S, constv, out);
}